// Round 4
// baseline (1044.808 us; speedup 1.0000x reference)
//
#include <hip/hip_runtime.h>

#define LTOK 4096
#define DHID 2048
#define HKN  16
#define HVN  32
#define DKK  128
#define NTOT 12288

typedef unsigned short u16;
typedef __attribute__((ext_vector_type(8))) short short8;
typedef __attribute__((ext_vector_type(8))) unsigned short u16x8;
typedef __attribute__((ext_vector_type(4))) unsigned short u16x4;
typedef __attribute__((ext_vector_type(4))) float f32x4;

__device__ __forceinline__ float b2f(u16 u) {
  unsigned int x = ((unsigned int)u) << 16;
  return __builtin_bit_cast(float, x);
}
__device__ __forceinline__ u16 f2bf(float f) {
  unsigned int u = __builtin_bit_cast(unsigned int, f);
  u += 0x7FFFu + ((u >> 16) & 1u);
  return (u16)(u >> 16);
}

template<int C> __device__ __forceinline__ float dppmv(float x) {
  int i = __builtin_amdgcn_update_dpp(0, __builtin_bit_cast(int, x), C, 0xF, 0xF, true);
  return __builtin_bit_cast(float, i);
}
__device__ __forceinline__ float red16(float x) {
  x += dppmv<0xB1>(x);
  x += dppmv<0x4E>(x);
  x += dppmv<0x124>(x);
  x += dppmv<0x128>(x);
  return x;
}

__device__ __forceinline__ void gld16(const void* g, void* l) {
  __builtin_amdgcn_global_load_lds((const __attribute__((address_space(1))) void*)g,
                                   (__attribute__((address_space(3))) void*)l, 16, 0, 0);
}

// swizzled LDS element offsets (XOR row-bits into 16B-slot bits); byte^=((r&7)<<4)
__device__ __forceinline__ int sw16(int r, int c, int rowc) { return (r * rowc + c) ^ ((r & 7) << 3); }

__device__ __forceinline__ void cstore(u16* C, size_t i, float v) { C[i] = f2bf(v); }
__device__ __forceinline__ void cstore(float* C, size_t i, float v) { C[i] = v; }

// ---------------- fp32 -> bf16 convert ----------------
__global__ __launch_bounds__(256)
void k_cvt(const float* __restrict__ s, u16* __restrict__ d, int n) {
  const int i = (blockIdx.x * 256 + threadIdx.x) * 4;
  const float4 v = *(const float4*)(s + i);
  ushort4 o;
  o.x = f2bf(v.x); o.y = f2bf(v.y); o.z = f2bf(v.z); o.w = f2bf(v.w);
  *(ushort4*)(d + i) = o;
}

// ---------------- fp32 [R][C] -> bf16 [C][R] transpose ----------------
__global__ __launch_bounds__(256)
void k_tr(const float* __restrict__ src, u16* __restrict__ dst, int R, int C) {
  __shared__ float tl[32][33];
  const int r0 = blockIdx.y * 32, c0 = blockIdx.x * 32;
  const int tr = threadIdx.x >> 3, tc = (threadIdx.x & 7) * 4;
  const float4 v = *(const float4*)(src + (size_t)(r0 + tr) * C + c0 + tc);
  tl[tr][tc] = v.x; tl[tr][tc + 1] = v.y; tl[tr][tc + 2] = v.z; tl[tr][tc + 3] = v.w;
  __syncthreads();
  ushort4 o;
  o.x = f2bf(tl[tc + 0][tr]); o.y = f2bf(tl[tc + 1][tr]);
  o.z = f2bf(tl[tc + 2][tr]); o.w = f2bf(tl[tc + 3][tr]);
  *(ushort4*)(dst + (size_t)(c0 + tr) * R + r0 + tc) = o;
}

// ---------------- bf16 MFMA GEMM: C[M][N] = A[M][K] * Bt[N][K]^T ----------------
template<typename OutT>
__global__ __launch_bounds__(256, 2)
void k_gemm(const u16* __restrict__ A, const u16* __restrict__ Bt, OutT* __restrict__ C,
            int M, int N, int K) {
  __shared__ u16 lA[128 * 32];
  __shared__ u16 lB[128 * 32];
  const int tid = threadIdx.x;
  const int lane = tid & 63, wid = tid >> 6;
  const int nt = blockIdx.x, mt = blockIdx.y;
  const int wm = (wid >> 1) * 64, wn = (wid & 1) * 64;
  const size_t sK = (size_t)K;
  const u16* aS = A + (size_t)(mt * 128 + wid * 32 + (lane >> 2)) * sK + (lane & 3) * 8;
  const u16* bS = Bt + (size_t)(nt * 128 + wid * 32 + (lane >> 2)) * sK + (lane & 3) * 8;
  u16* lAw = lA + wid * 1024;
  u16* lBw = lB + wid * 1024;
  f32x4 acc[4][4] = {};
  const int aoff = (lane & 15) * 32 + (lane >> 4) * 8;

  for (int k0 = 0; k0 < K; k0 += 32) {
    gld16(aS + k0, lAw);
    gld16(aS + k0 + 16 * sK, lAw + 512);
    gld16(bS + k0, lBw);
    gld16(bS + k0 + 16 * sK, lBw + 512);
    __syncthreads();
    short8 af[4], bfv[4];
#pragma unroll
    for (int i = 0; i < 4; ++i) {
      af[i]  = *(const short8*)&lA[(wm + i * 16) * 32 + aoff];
      bfv[i] = *(const short8*)&lB[(wn + i * 16) * 32 + aoff];
    }
#pragma unroll
    for (int i = 0; i < 4; ++i)
#pragma unroll
      for (int j = 0; j < 4; ++j)
        acc[i][j] = __builtin_amdgcn_mfma_f32_16x16x32_bf16(af[i], bfv[j], acc[i][j], 0, 0, 0);
    __syncthreads();
  }
  const int r0 = mt * 128 + wm + (lane >> 4) * 4;
  const int c0 = nt * 128 + wn + (lane & 15);
#pragma unroll
  for (int i = 0; i < 4; ++i)
#pragma unroll
    for (int j = 0; j < 4; ++j)
#pragma unroll
      for (int e = 0; e < 4; ++e)
        cstore(C, (size_t)(r0 + i * 16 + e) * N + c0 + j * 16, acc[i][j][e]);
}

// ---------------- beta / g (log-decay): [L,2048]@[2048,32] x2 + activations ----------------
__global__ __launch_bounds__(256)
void k_ba(const float* __restrict__ h, const float* __restrict__ Wb, const float* __restrict__ Wa,
          const float* __restrict__ A_log, const float* __restrict__ dtb,
          float* __restrict__ beta, float* __restrict__ g_out) {
  const int w = threadIdx.x >> 6, lane = threadIdx.x & 63;
  const int t = blockIdx.x * 4 + w;
  const int j = lane & 31;
  const bool isB = lane < 32;
  const float* __restrict__ hr = h + (size_t)t * DHID;
  const float* Wc = isB ? Wb : Wa;
  float acc = 0.f;
  for (int kk = 0; kk < DHID; ++kk) acc = fmaf(hr[kk], Wc[(size_t)kk * HVN + j], acc);
  if (isB) {
    beta[(size_t)t * HVN + j] = 1.f / (1.f + expf(-acc));
  } else {
    float xx = acc + dtb[j];
    float sp = (xx > 20.f) ? xx : log1pf(expf(xx));
    g_out[(size_t)t * HVN + j] = -expf(A_log[j]) * sp;   // g = log(decay) <= 0
  }
}

// ---------------- in-place l2norm of q (scaled) and k heads ----------------
__global__ __launch_bounds__(256)
void k_l2n(u16* __restrict__ qkvz) {
  const int w = threadIdx.x >> 6, lane = threadIdx.x & 63;
  const int r = blockIdx.x * 4 + w;
  const int isK = r >> 16;
  const int rr = r & 65535;
  const int t = rr >> 4, hd = rr & 15;
  u16* p = qkvz + (size_t)t * NTOT + isK * 2048 + hd * DKK + lane * 2;
  float a = b2f(p[0]), b = b2f(p[1]);
  float ss = a * a + b * b;
  ss = red16(ss);
  ss += __shfl_xor(ss, 16);
  ss += __shfl_xor(ss, 32);
  const float sc = rsqrtf(ss + 1e-6f) * (isK ? 1.f : 0.08838834764831845f);
  p[0] = f2bf(a * sc); p[1] = f2bf(b * sc);
}

#define MFMA16(a, b, c) __builtin_amdgcn_mfma_f32_16x16x32_bf16(a, b, c, 0, 0, 0)

// ---------------- chunk solve (parallel): per (hv, chunk n) ----------------
__global__ __launch_bounds__(256)
void k_r1(const u16* __restrict__ qkvz, const float* __restrict__ beta_g,
          const float* __restrict__ g_g, u16* __restrict__ UM_g, float* __restrict__ cumL_g) {
  const int pair = blockIdx.x;          // hv*64 + n
  const int hv = pair >> 6, n = pair & 63;
  const int hk = hv >> 1;
  const int t0 = n * 64;
  const int tid = threadIdx.x, lane = tid & 63, wv = tid >> 6;
  const int fr = lane & 15, fq = lane >> 4;

  __shared__ __align__(16) u16 Xb[256 * 64];
  __shared__ __align__(16) u16 Dbuf0[64 * 64 * 2];
  __shared__ __align__(16) u16 Dbuf1[64 * 64 * 2];
  __shared__ float Lc[64];
  __shared__ float Bc[64];
  u16* Kl = Dbuf0;

  const int j = tid & 63, h = tid >> 6;
  const u16* kg = qkvz + (size_t)(t0 + j) * NTOT + 2048 + hk * DKK + h * 32;
  const u16* vg = qkvz + (size_t)(t0 + j) * NTOT + 4096 + hv * DKK + h * 32;
  u16x8 kv[4], vv[4];
#pragma unroll
  for (int i = 0; i < 4; ++i) { kv[i] = *(const u16x8*)(kg + i * 8); vv[i] = *(const u16x8*)(vg + i * 8); }
  if (tid < 64) {
    Lc[tid] = g_g[(size_t)(t0 + tid) * HVN + hv];
    Bc[tid] = beta_g[(size_t)(t0 + tid) * HVN + hv];
  }
#pragma unroll
  for (int i = 0; i < 4; ++i) *(u16x8*)&Kl[sw16(j, h * 32 + i * 8, 128)] = kv[i];
  __syncthreads();
  if (tid == 0) { float a = 0.f; for (int t = 0; t < 64; ++t) { a += Lc[t]; Lc[t] = a; } }
  __syncthreads();
  if (tid < 64) cumL_g[(size_t)pair * 64 + tid] = Lc[tid];

  {
    const float bj = Bc[j];
    const float mj = bj * __expf(Lc[j]);
#pragma unroll
    for (int i = 0; i < 4; ++i)
#pragma unroll
      for (int e = 0; e < 8; ++e) {
        int c = h * 32 + i * 8 + e;
        Xb[sw16(c, j, 64)] = f2bf(bj * b2f(vv[i][e]));
        Xb[sw16(128 + c, j, 64)] = f2bf(mj * b2f(kv[i][e]));
      }
  }
  f32x4 kk[4] = {};
#pragma unroll
  for (int ks = 0; ks < 4; ++ks) {
    short8 afr = *(const short8*)&Kl[sw16(wv * 16 + fr, ks * 32 + fq * 8, 128)];
#pragma unroll
    for (int ct = 0; ct < 4; ++ct) {
      short8 bfr = *(const short8*)&Kl[sw16(ct * 16 + fr, ks * 32 + fq * 8, 128)];
      kk[ct] = MFMA16(afr, bfr, kk[ct]);
    }
  }
  __syncthreads();

  f32x4 acc[16];
#pragma unroll
  for (int ct = 0; ct < 16; ++ct) {
    u16x4 xi = *(const u16x4*)&Xb[sw16(ct * 16 + fr, wv * 16 + fq * 4, 64)];
    acc[ct][0] = b2f(xi[0]); acc[ct][1] = b2f(xi[1]); acc[ct][2] = b2f(xi[2]); acc[ct][3] = b2f(xi[3]);
  }
#pragma unroll
  for (int ct = 0; ct < 4; ++ct) {
    const int s = ct * 16 + fr;
    u16x4 pk;
#pragma unroll
    for (int e = 0; e < 4; ++e) {
      const int t = wv * 16 + fq * 4 + e;
      float v = (s < t) ? -Bc[t] * __expf(Lc[t] - Lc[s]) * kk[ct][e] : 0.f;
      pk[e] = f2bf(v);
      Dbuf0[sw16(t, s, 64)] = pk[e];
    }
    *(u16x4*)&Dbuf0[4096 + sw16(s, wv * 16 + fq * 4, 64)] = pk;
  }
  __syncthreads();

  u16* DA = Dbuf0;
  u16* DB = Dbuf1;
  for (int stg = 0; stg < 6; ++stg) {
    u16* Dr = DA;
    u16* Dc = DA + 4096;
    short8 da0 = *(const short8*)&Dr[sw16(wv * 16 + fr, 0 + fq * 8, 64)];
    short8 da1 = *(const short8*)&Dr[sw16(wv * 16 + fr, 32 + fq * 8, 64)];
#pragma unroll
    for (int ct = 0; ct < 16; ++ct) {
      short8 b0 = *(const short8*)&Xb[sw16(ct * 16 + fr, 0 + fq * 8, 64)];
      short8 b1 = *(const short8*)&Xb[sw16(ct * 16 + fr, 32 + fq * 8, 64)];
      acc[ct] = MFMA16(da0, b0, acc[ct]);
      acc[ct] = MFMA16(da1, b1, acc[ct]);
    }
    f32x4 sq[4] = {};
    if (stg < 5) {
#pragma unroll
      for (int ct = 0; ct < 4; ++ct) {
        short8 sb0 = *(const short8*)&Dc[sw16(ct * 16 + fr, 0 + fq * 8, 64)];
        short8 sb1 = *(const short8*)&Dc[sw16(ct * 16 + fr, 32 + fq * 8, 64)];
        sq[ct] = MFMA16(da0, sb0, sq[ct]);
        sq[ct] = MFMA16(da1, sb1, sq[ct]);
      }
    }
    __syncthreads();
#pragma unroll
    for (int ct = 0; ct < 16; ++ct) {
      u16x4 pk;
      pk[0] = f2bf(acc[ct][0]); pk[1] = f2bf(acc[ct][1]); pk[2] = f2bf(acc[ct][2]); pk[3] = f2bf(acc[ct][3]);
      *(u16x4*)&Xb[sw16(ct * 16 + fr, wv * 16 + fq * 4, 64)] = pk;
    }
    if (stg < 5) {
#pragma unroll
      for (int ct = 0; ct < 4; ++ct) {
        u16x4 pk;
        pk[0] = f2bf(sq[ct][0]); pk[1] = f2bf(sq[ct][1]); pk[2] = f2bf(sq[ct][2]); pk[3] = f2bf(sq[ct][3]);
        *(u16x4*)&(DB + 4096)[sw16(ct * 16 + fr, wv * 16 + fq * 4, 64)] = pk;
#pragma unroll
        for (int e = 0; e < 4; ++e) DB[sw16(wv * 16 + fq * 4 + e, ct * 16 + fr, 64)] = pk[e];
      }
    }
    __syncthreads();
    u16* tmp = DA; DA = DB; DB = tmp;
  }

#pragma unroll
  for (int ct = 0; ct < 16; ++ct) {
    const int c = ct * 16 + fr;
#pragma unroll
    for (int e = 0; e < 4; ++e) {
      const int t = wv * 16 + fq * 4 + e;
      float v = acc[ct][e];
      if (ct >= 8) v = -v;
      UM_g[((size_t)pair * 64 + t) * 256 + c] = f2bf(v);
    }
  }
}

// ---------------- sequential chunk scan: one block per head, 8 waves ----------------
// S^T held in register MFMA accumulators (wave w owns dk-tile w), bf16 mirror in LDS.
// Per chunk: ph1 {M@S->delta, Q@S, QK^T->G}; ph2 {o += G@delta -> store, S = eC*S + Kbar^T@delta};
// next chunk's Q/K/M/U prefetched to regs at chunk top (T14), LDS-written after ph2.
__global__ __launch_bounds__(512)
void k_r2(const u16* __restrict__ qkvz, const u16* __restrict__ UM_g,
          const float* __restrict__ cumL_g, u16* __restrict__ core) {
  const int hv = blockIdx.x;
  const int hk = hv >> 1;
  const int tid = threadIdx.x, lane = tid & 63, w = tid >> 6;   // w 0..7
  const int fr = lane & 15, fq = lane >> 4;
  const int j = tid & 63, h = tid >> 6;                          // staging coords

  __shared__ __align__(16) u16 Ql[64 * 128];   // q rows [t][dk] swz
  __shared__ __align__(16) u16 Kl[64 * 128];   // k rows
  __shared__ __align__(16) u16 Ml[64 * 128];   // -M rows
  __shared__ __align__(16) u16 Kt[128 * 64];   // Kbar^T [dk][t]
  __shared__ __align__(16) u16 Ul[128 * 64];   // U^T [dv][t] bf16
  __shared__ __align__(16) u16 Gl[64 * 64];    // G [t][s]
  __shared__ __align__(16) u16 dT[128 * 64];   // delta^T [dv][t]
  __shared__ __align__(16) u16 SbT[128 * 128]; // S^T [dv][dk] bf16
  __shared__ float Lc[64];

  f32x4 sacc[8];
#pragma unroll
  for (int jt = 0; jt < 8; ++jt) sacc[jt] = (f32x4){0.f, 0.f, 0.f, 0.f};
  for (int i = tid; i < 128 * 128; i += 512) SbT[i] = 0;

  u16x8 pQ0, pQ1, pK0, pK1, pM0, pM1, pU0, pU1;
  float pL, pL63;

#define PREF(nn) {                                                            \
    const int nc = ((nn) < 64) ? (nn) : 63;                                   \
    const int pr = hv * 64 + nc; const int tt0 = nc * 64;                     \
    const u16* qg = qkvz + (size_t)(tt0 + j) * NTOT + hk * DKK + h * 16;      \
    const u16* mg = UM_g + ((size_t)pr * 64 + j) * 256 + h * 16;              \
    pQ0 = *(const u16x8*)qg;          pQ1 = *(const u16x8*)(qg + 8);          \
    pK0 = *(const u16x8*)(qg + 2048); pK1 = *(const u16x8*)(qg + 2056);       \
    pU0 = *(const u16x8*)mg;          pU1 = *(const u16x8*)(mg + 8);          \
    pM0 = *(const u16x8*)(mg + 128);  pM1 = *(const u16x8*)(mg + 136);        \
    pL = cumL_g[(size_t)pr * 64 + j]; pL63 = cumL_g[(size_t)pr * 64 + 63]; }

#define STW() {                                                               \
    *(u16x8*)&Ql[sw16(j, h * 16, 128)] = pQ0;                                 \
    *(u16x8*)&Ql[sw16(j, h * 16 + 8, 128)] = pQ1;                             \
    *(u16x8*)&Kl[sw16(j, h * 16, 128)] = pK0;                                 \
    *(u16x8*)&Kl[sw16(j, h * 16 + 8, 128)] = pK1;                             \
    *(u16x8*)&Ml[sw16(j, h * 16, 128)] = pM0;                                 \
    *(u16x8*)&Ml[sw16(j, h * 16 + 8, 128)] = pM1;                             \
    const float sc = __expf(pL63 - pL);                                       \
    _Pragma("unroll")                                                         \
    for (int e = 0; e < 8; ++e) {                                             \
      Kt[sw16(h * 16 + e, j, 64)] = f2bf(sc * b2f(pK0[e]));                   \
      Kt[sw16(h * 16 + 8 + e, j, 64)] = f2bf(sc * b2f(pK1[e]));               \
      Ul[sw16(h * 16 + e, j, 64)] = pU0[e];                                   \
      Ul[sw16(h * 16 + 8 + e, j, 64)] = pU1[e];                               \
    }                                                                         \
    if (h == 0) Lc[j] = pL; }

  PREF(0)
  STW()
  __syncthreads();

  for (int n = 0; n < 64; ++n) {
    const int t0 = n * 64;
    const float curL63 = pL63;
    PREF(n + 1)

    // ---- ph1 ----
    short8 bs0 = *(const short8*)&SbT[sw16(w * 16 + fr, 0 + fq * 8, 128)];
    short8 bs1 = *(const short8*)&SbT[sw16(w * 16 + fr, 32 + fq * 8, 128)];
    short8 bs2 = *(const short8*)&SbT[sw16(w * 16 + fr, 64 + fq * 8, 128)];
    short8 bs3 = *(const short8*)&SbT[sw16(w * 16 + fr, 96 + fq * 8, 128)];
    f32x4 oacc[4];
#pragma unroll
    for (int ct = 0; ct < 4; ++ct) {
      u16x4 uv = *(const u16x4*)&Ul[sw16(w * 16 + fr, ct * 16 + fq * 4, 64)];
      f32x4 dc;
      dc[0] = b2f(uv[0]); dc[1] = b2f(uv[1]); dc[2] = b2f(uv[2]); dc[3] = b2f(uv[3]);
      f32x4 oc = {};
#pragma unroll
      for (int ks = 0; ks < 4; ++ks) {
        short8 aq = *(const short8*)&Ql[sw16(ct * 16 + fr, ks * 32 + fq * 8, 128)];
        short8 am = *(const short8*)&Ml[sw16(ct * 16 + fr, ks * 32 + fq * 8, 128)];
        short8 bb = (ks == 0) ? bs0 : (ks == 1) ? bs1 : (ks == 2) ? bs2 : bs3;
        oc = MFMA16(aq, bb, oc);
        dc = MFMA16(am, bb, dc);
      }
#pragma unroll
      for (int e = 0; e < 4; ++e) oc[e] *= __expf(Lc[ct * 16 + fq * 4 + e]);
      oacc[ct] = oc;
      u16x4 pk;
      pk[0] = f2bf(dc[0]); pk[1] = f2bf(dc[1]); pk[2] = f2bf(dc[2]); pk[3] = f2bf(dc[3]);
      *(u16x4*)&dT[sw16(w * 16 + fr, ct * 16 + fq * 4, 64)] = pk;
    }
    {
      const int tq = w >> 1, tsb = (w & 1) * 2;
      f32x4 kk0 = {}, kk1 = {};
#pragma unroll
      for (int ks = 0; ks < 4; ++ks) {
        short8 aq = *(const short8*)&Ql[sw16(tq * 16 + fr, ks * 32 + fq * 8, 128)];
        short8 b0 = *(const short8*)&Kl[sw16(tsb * 16 + fr, ks * 32 + fq * 8, 128)];
        short8 b1 = *(const short8*)&Kl[sw16((tsb + 1) * 16 + fr, ks * 32 + fq * 8, 128)];
        kk0 = MFMA16(aq, b0, kk0);
        kk1 = MFMA16(aq, b1, kk1);
      }
#pragma unroll
      for (int e = 0; e < 4; ++e) {
        const int t = tq * 16 + fq * 4 + e;
        const float Lt = Lc[t];
        const int s0 = tsb * 16 + fr;
        const int s1 = s0 + 16;
        float v0 = (s0 <= t) ? kk0[e] * __expf(Lt - Lc[s0]) : 0.f;
        float v1 = (s1 <= t) ? kk1[e] * __expf(Lt - Lc[s1]) : 0.f;
        Gl[sw16(t, s0, 64)] = f2bf(v0);
        Gl[sw16(t, s1, 64)] = f2bf(v1);
      }
    }
    __syncthreads();

    // ---- ph2 ----
    short8 bd0 = *(const short8*)&dT[sw16(w * 16 + fr, 0 + fq * 8, 64)];
    short8 bd1 = *(const short8*)&dT[sw16(w * 16 + fr, 32 + fq * 8, 64)];
#pragma unroll
    for (int ct = 0; ct < 4; ++ct) {
      short8 ag0 = *(const short8*)&Gl[sw16(ct * 16 + fr, 0 + fq * 8, 64)];
      short8 ag1 = *(const short8*)&Gl[sw16(ct * 16 + fr, 32 + fq * 8, 64)];
      f32x4 oc = oacc[ct];
      oc = MFMA16(ag0, bd0, oc);
      oc = MFMA16(ag1, bd1, oc);
#pragma unroll
      for (int e = 0; e < 4; ++e)
        core[(size_t)(t0 + ct * 16 + fq * 4 + e) * 4096 + hv * DKK + w * 16 + fr] = f2bf(oc[e]);
    }
    {
      const float eC = __expf(curL63);
      short8 ak0 = *(const short8*)&Kt[sw16(w * 16 + fr, 0 + fq * 8, 64)];
      short8 ak1 = *(const short8*)&Kt[sw16(w * 16 + fr, 32 + fq * 8, 64)];
#pragma unroll
      for (int jt = 0; jt < 8; ++jt) {
        short8 d0 = *(const short8*)&dT[sw16(jt * 16 + fr, 0 + fq * 8, 64)];
        short8 d1 = *(const short8*)&dT[sw16(jt * 16 + fr, 32 + fq * 8, 64)];
        f32x4 sa = sacc[jt];
#pragma unroll
        for (int e = 0; e < 4; ++e) sa[e] *= eC;
        sa = MFMA16(ak0, d0, sa);
        sa = MFMA16(ak1, d1, sa);
        sacc[jt] = sa;
        u16x4 pk;
        pk[0] = f2bf(sa[0]); pk[1] = f2bf(sa[1]); pk[2] = f2bf(sa[2]); pk[3] = f2bf(sa[3]);
        *(u16x4*)&SbT[sw16(jt * 16 + fr, w * 16 + fq * 4, 128)] = pk;
      }
    }
    __syncthreads();
    STW()
    __syncthreads();
  }
#undef PREF
#undef STW
}

// ---------------- gated RMSNorm: x = rmsnorm(core * silu(z)) * w ----------------
__global__ __launch_bounds__(256)
void k_gnorm(const u16* __restrict__ core, const u16* __restrict__ qkvz,
             const float* __restrict__ nw, u16* __restrict__ x) {
  const int hv = blockIdx.y;
  const int t = blockIdx.x * 64 + (threadIdx.x >> 2);
  const int q = threadIdx.x & 3;
  const u16* cp = core + (size_t)t * 4096 + hv * DKK + q * 32;
  const u16* zp = qkvz + (size_t)t * NTOT + 8192 + hv * DKK + q * 32;
  float xv[32];
  float ss = 0.f;
#pragma unroll
  for (int i = 0; i < 4; ++i) {
    u16x8 cv = *(const u16x8*)(cp + i * 8);
    u16x8 zv = *(const u16x8*)(zp + i * 8);
#pragma unroll
    for (int e = 0; e < 8; ++e) {
      float z = b2f(zv[e]);
      float xx = b2f(cv[e]) * (z / (1.f + __expf(-z)));
      xv[i * 8 + e] = xx;
      ss = fmaf(xx, xx, ss);
    }
  }
  ss += dppmv<0xB1>(ss);
  ss += dppmv<0x4E>(ss);
  const float scl = rsqrtf(ss * (1.f / 128.f) + 1e-6f);
  u16* xo = x + (size_t)t * 4096 + hv * DKK + q * 32;
#pragma unroll
  for (int i = 0; i < 4; ++i) {
    u16x8 pk;
#pragma unroll
    for (int e = 0; e < 8; ++e) pk[e] = f2bf(xv[i * 8 + e] * scl * nw[q * 32 + i * 8 + e]);
    *(u16x8*)(xo + i * 8) = pk;
  }
}

extern "C" void kernel_launch(void* const* d_in, const int* in_sizes, int n_in,
                              void* d_out, int out_size, void* d_ws, size_t ws_size,
                              hipStream_t stream) {
  const float* h    = (const float*)d_in[0];
  const float* Wq   = (const float*)d_in[1];
  const float* Wk   = (const float*)d_in[2];
  const float* Wv   = (const float*)d_in[3];
  const float* Wz   = (const float*)d_in[4];
  const float* Wb   = (const float*)d_in[5];
  const float* Wa   = (const float*)d_in[6];
  const float* Alog = (const float*)d_in[7];
  const float* dtb  = (const float*)d_in[8];
  const float* nw   = (const float*)d_in[9];
  const float* Wo   = (const float*)d_in[10];
  char* ws = (char*)d_ws;
  u16* h_bf  = (u16*)(ws);
  u16* Wt    = (u16*)(ws + 16777216ull);
  u16* UM    = (u16*)(ws);                    // [2048][64][256] bf16 = 64MB (after GEMM)
  u16* Wto   = (u16*)(ws + 67108864ull);
  u16* qkvz  = (u16*)(ws + 83886080ull);
  u16* core  = (u16*)(ws + 184549376ull);     // [4096][4096] bf16 row-major
  u16* xbuf  = (u16*)(ws + 16777216ull);      // aliases UM tail (dead after R2)
  float* beta  = (float*)(ws + 218103808ull);
  float* g     = (float*)(ws + 218103808ull + 524288ull);
  float* cumL  = (float*)(ws + 218103808ull + 1048576ull);

  k_cvt<<<8192, 256, 0, stream>>>(h, h_bf, LTOK * DHID);
  k_tr<<<dim3(64, 64), 256, 0, stream>>>(Wq, Wt, 2048, 2048);
  k_tr<<<dim3(64, 64), 256, 0, stream>>>(Wk, Wt + 2048ull * 2048, 2048, 2048);
  k_tr<<<dim3(128, 64), 256, 0, stream>>>(Wv, Wt + 4096ull * 2048, 2048, 4096);
  k_tr<<<dim3(128, 64), 256, 0, stream>>>(Wz, Wt + 8192ull * 2048, 2048, 4096);
  k_tr<<<dim3(64, 128), 256, 0, stream>>>(Wo, Wto, 4096, 2048);
  k_gemm<u16><<<dim3(96, 32), 256, 0, stream>>>(h_bf, Wt, qkvz, 4096, 12288, 2048);
  k_ba<<<1024, 256, 0, stream>>>(h, Wb, Wa, Alog, dtb, beta, g);
  k_l2n<<<32768, 256, 0, stream>>>(qkvz);
  k_r1<<<2048, 256, 0, stream>>>(qkvz, beta, g, UM, cumL);
  k_r2<<<32, 512, 0, stream>>>(qkvz, UM, cumL, core);
  k_gnorm<<<dim3(64, 32), 256, 0, stream>>>(core, qkvz, nw, xbuf);
  k_gemm<float><<<dim3(16, 32), 256, 0, stream>>>(xbuf, Wto, (float*)d_out, 4096, 2048, 4096);
}

// Round 5
// 917.841 us; speedup vs baseline: 1.1383x; 1.1383x over previous
//
#include <hip/hip_runtime.h>

#define LTOK 4096
#define DHID 2048
#define HKN  16
#define HVN  32
#define DKK  128
#define NTOT 12288

typedef unsigned short u16;
typedef __attribute__((ext_vector_type(8))) short short8;
typedef __attribute__((ext_vector_type(8))) unsigned short u16x8;
typedef __attribute__((ext_vector_type(4))) unsigned short u16x4;
typedef __attribute__((ext_vector_type(4))) float f32x4;

__device__ __forceinline__ float b2f(u16 u) {
  unsigned int x = ((unsigned int)u) << 16;
  return __builtin_bit_cast(float, x);
}
__device__ __forceinline__ u16 f2bf(float f) {
  unsigned int u = __builtin_bit_cast(unsigned int, f);
  u += 0x7FFFu + ((u >> 16) & 1u);
  return (u16)(u >> 16);
}

template<int C> __device__ __forceinline__ float dppmv(float x) {
  int i = __builtin_amdgcn_update_dpp(0, __builtin_bit_cast(int, x), C, 0xF, 0xF, true);
  return __builtin_bit_cast(float, i);
}
__device__ __forceinline__ float red16(float x) {
  x += dppmv<0xB1>(x);
  x += dppmv<0x4E>(x);
  x += dppmv<0x124>(x);
  x += dppmv<0x128>(x);
  return x;
}

__device__ __forceinline__ void gld16(const void* g, void* l) {
  __builtin_amdgcn_global_load_lds((const __attribute__((address_space(1))) void*)g,
                                   (__attribute__((address_space(3))) void*)l, 16, 0, 0);
}

// swizzled LDS element offsets (XOR row-bits into 16B-slot bits); byte^=((r&7)<<4)
__device__ __forceinline__ int sw16(int r, int c, int rowc) { return (r * rowc + c) ^ ((r & 7) << 3); }

__device__ __forceinline__ void cstore(u16* C, size_t i, float v) { C[i] = f2bf(v); }
__device__ __forceinline__ void cstore(float* C, size_t i, float v) { C[i] = v; }

// ---------------- fp32 -> bf16 convert ----------------
__global__ __launch_bounds__(256)
void k_cvt(const float* __restrict__ s, u16* __restrict__ d, int n) {
  const int i = (blockIdx.x * 256 + threadIdx.x) * 4;
  const float4 v = *(const float4*)(s + i);
  ushort4 o;
  o.x = f2bf(v.x); o.y = f2bf(v.y); o.z = f2bf(v.z); o.w = f2bf(v.w);
  *(ushort4*)(d + i) = o;
}

// ---------------- fp32 [R][C] -> bf16 [C][R] transpose ----------------
__global__ __launch_bounds__(256)
void k_tr(const float* __restrict__ src, u16* __restrict__ dst, int R, int C) {
  __shared__ float tl[32][33];
  const int r0 = blockIdx.y * 32, c0 = blockIdx.x * 32;
  const int tr = threadIdx.x >> 3, tc = (threadIdx.x & 7) * 4;
  const float4 v = *(const float4*)(src + (size_t)(r0 + tr) * C + c0 + tc);
  tl[tr][tc] = v.x; tl[tr][tc + 1] = v.y; tl[tr][tc + 2] = v.z; tl[tr][tc + 3] = v.w;
  __syncthreads();
  ushort4 o;
  o.x = f2bf(tl[tc + 0][tr]); o.y = f2bf(tl[tc + 1][tr]);
  o.z = f2bf(tl[tc + 2][tr]); o.w = f2bf(tl[tc + 3][tr]);
  *(ushort4*)(dst + (size_t)(c0 + tr) * R + r0 + tc) = o;
}

// ---------------- bf16 MFMA GEMM: C[M][N] = A[M][K] * Bt[N][K]^T ----------------
template<typename OutT>
__global__ __launch_bounds__(256, 2)
void k_gemm(const u16* __restrict__ A, const u16* __restrict__ Bt, OutT* __restrict__ C,
            int M, int N, int K) {
  __shared__ u16 lA[128 * 32];
  __shared__ u16 lB[128 * 32];
  const int tid = threadIdx.x;
  const int lane = tid & 63, wid = tid >> 6;
  const int nt = blockIdx.x, mt = blockIdx.y;
  const int wm = (wid >> 1) * 64, wn = (wid & 1) * 64;
  const size_t sK = (size_t)K;
  const u16* aS = A + (size_t)(mt * 128 + wid * 32 + (lane >> 2)) * sK + (lane & 3) * 8;
  const u16* bS = Bt + (size_t)(nt * 128 + wid * 32 + (lane >> 2)) * sK + (lane & 3) * 8;
  u16* lAw = lA + wid * 1024;
  u16* lBw = lB + wid * 1024;
  f32x4 acc[4][4] = {};
  const int aoff = (lane & 15) * 32 + (lane >> 4) * 8;

  for (int k0 = 0; k0 < K; k0 += 32) {
    gld16(aS + k0, lAw);
    gld16(aS + k0 + 16 * sK, lAw + 512);
    gld16(bS + k0, lBw);
    gld16(bS + k0 + 16 * sK, lBw + 512);
    __syncthreads();
    short8 af[4], bfv[4];
#pragma unroll
    for (int i = 0; i < 4; ++i) {
      af[i]  = *(const short8*)&lA[(wm + i * 16) * 32 + aoff];
      bfv[i] = *(const short8*)&lB[(wn + i * 16) * 32 + aoff];
    }
#pragma unroll
    for (int i = 0; i < 4; ++i)
#pragma unroll
      for (int j = 0; j < 4; ++j)
        acc[i][j] = __builtin_amdgcn_mfma_f32_16x16x32_bf16(af[i], bfv[j], acc[i][j], 0, 0, 0);
    __syncthreads();
  }
  const int r0 = mt * 128 + wm + (lane >> 4) * 4;
  const int c0 = nt * 128 + wn + (lane & 15);
#pragma unroll
  for (int i = 0; i < 4; ++i)
#pragma unroll
    for (int j = 0; j < 4; ++j)
#pragma unroll
      for (int e = 0; e < 4; ++e)
        cstore(C, (size_t)(r0 + i * 16 + e) * N + c0 + j * 16, acc[i][j][e]);
}

// ---------------- beta / g (log-decay): [L,2048]@[2048,32] x2 + activations ----------------
__global__ __launch_bounds__(256)
void k_ba(const float* __restrict__ h, const float* __restrict__ Wb, const float* __restrict__ Wa,
          const float* __restrict__ A_log, const float* __restrict__ dtb,
          float* __restrict__ beta, float* __restrict__ g_out) {
  const int w = threadIdx.x >> 6, lane = threadIdx.x & 63;
  const int t = blockIdx.x * 4 + w;
  const int j = lane & 31;
  const bool isB = lane < 32;
  const float* __restrict__ hr = h + (size_t)t * DHID;
  const float* Wc = isB ? Wb : Wa;
  float acc = 0.f;
  for (int kk = 0; kk < DHID; ++kk) acc = fmaf(hr[kk], Wc[(size_t)kk * HVN + j], acc);
  if (isB) {
    beta[(size_t)t * HVN + j] = 1.f / (1.f + expf(-acc));
  } else {
    float xx = acc + dtb[j];
    float sp = (xx > 20.f) ? xx : log1pf(expf(xx));
    g_out[(size_t)t * HVN + j] = -expf(A_log[j]) * sp;   // g = log(decay) <= 0
  }
}

// ---------------- in-place l2norm of q (scaled) and k heads ----------------
__global__ __launch_bounds__(256)
void k_l2n(u16* __restrict__ qkvz) {
  const int w = threadIdx.x >> 6, lane = threadIdx.x & 63;
  const int r = blockIdx.x * 4 + w;
  const int isK = r >> 16;
  const int rr = r & 65535;
  const int t = rr >> 4, hd = rr & 15;
  u16* p = qkvz + (size_t)t * NTOT + isK * 2048 + hd * DKK + lane * 2;
  float a = b2f(p[0]), b = b2f(p[1]);
  float ss = a * a + b * b;
  ss = red16(ss);
  ss += __shfl_xor(ss, 16);
  ss += __shfl_xor(ss, 32);
  const float sc = rsqrtf(ss + 1e-6f) * (isK ? 1.f : 0.08838834764831845f);
  p[0] = f2bf(a * sc); p[1] = f2bf(b * sc);
}

#define MFMA16(a, b, c) __builtin_amdgcn_mfma_f32_16x16x32_bf16(a, b, c, 0, 0, 0)

// ---------------- chunk solve (parallel): per (hv, chunk n) ----------------
__global__ __launch_bounds__(256)
void k_r1(const u16* __restrict__ qkvz, const float* __restrict__ beta_g,
          const float* __restrict__ g_g, u16* __restrict__ UM_g, float* __restrict__ cumL_g) {
  const int pair = blockIdx.x;          // hv*64 + n
  const int hv = pair >> 6, n = pair & 63;
  const int hk = hv >> 1;
  const int t0 = n * 64;
  const int tid = threadIdx.x, lane = tid & 63, wv = tid >> 6;
  const int fr = lane & 15, fq = lane >> 4;

  __shared__ __align__(16) u16 Xb[256 * 64];
  __shared__ __align__(16) u16 Dbuf0[64 * 64 * 2];
  __shared__ __align__(16) u16 Dbuf1[64 * 64 * 2];
  __shared__ float Lc[64];
  __shared__ float Bc[64];
  u16* Kl = Dbuf0;

  const int j = tid & 63, h = tid >> 6;
  const u16* kg = qkvz + (size_t)(t0 + j) * NTOT + 2048 + hk * DKK + h * 32;
  const u16* vg = qkvz + (size_t)(t0 + j) * NTOT + 4096 + hv * DKK + h * 32;
  u16x8 kv[4], vv[4];
#pragma unroll
  for (int i = 0; i < 4; ++i) { kv[i] = *(const u16x8*)(kg + i * 8); vv[i] = *(const u16x8*)(vg + i * 8); }
  if (tid < 64) {
    Lc[tid] = g_g[(size_t)(t0 + tid) * HVN + hv];
    Bc[tid] = beta_g[(size_t)(t0 + tid) * HVN + hv];
  }
#pragma unroll
  for (int i = 0; i < 4; ++i) *(u16x8*)&Kl[sw16(j, h * 32 + i * 8, 128)] = kv[i];
  __syncthreads();
  if (tid == 0) { float a = 0.f; for (int t = 0; t < 64; ++t) { a += Lc[t]; Lc[t] = a; } }
  __syncthreads();
  if (tid < 64) cumL_g[(size_t)pair * 64 + tid] = Lc[tid];

  {
    const float bj = Bc[j];
    const float mj = bj * __expf(Lc[j]);
#pragma unroll
    for (int i = 0; i < 4; ++i)
#pragma unroll
      for (int e = 0; e < 8; ++e) {
        int c = h * 32 + i * 8 + e;
        Xb[sw16(c, j, 64)] = f2bf(bj * b2f(vv[i][e]));
        Xb[sw16(128 + c, j, 64)] = f2bf(mj * b2f(kv[i][e]));
      }
  }
  f32x4 kk[4] = {};
#pragma unroll
  for (int ks = 0; ks < 4; ++ks) {
    short8 afr = *(const short8*)&Kl[sw16(wv * 16 + fr, ks * 32 + fq * 8, 128)];
#pragma unroll
    for (int ct = 0; ct < 4; ++ct) {
      short8 bfr = *(const short8*)&Kl[sw16(ct * 16 + fr, ks * 32 + fq * 8, 128)];
      kk[ct] = MFMA16(afr, bfr, kk[ct]);
    }
  }
  __syncthreads();

  f32x4 acc[16];
#pragma unroll
  for (int ct = 0; ct < 16; ++ct) {
    u16x4 xi = *(const u16x4*)&Xb[sw16(ct * 16 + fr, wv * 16 + fq * 4, 64)];
    acc[ct][0] = b2f(xi[0]); acc[ct][1] = b2f(xi[1]); acc[ct][2] = b2f(xi[2]); acc[ct][3] = b2f(xi[3]);
  }
#pragma unroll
  for (int ct = 0; ct < 4; ++ct) {
    const int s = ct * 16 + fr;
    u16x4 pk;
#pragma unroll
    for (int e = 0; e < 4; ++e) {
      const int t = wv * 16 + fq * 4 + e;
      float v = (s < t) ? -Bc[t] * __expf(Lc[t] - Lc[s]) * kk[ct][e] : 0.f;
      pk[e] = f2bf(v);
      Dbuf0[sw16(t, s, 64)] = pk[e];
    }
    *(u16x4*)&Dbuf0[4096 + sw16(s, wv * 16 + fq * 4, 64)] = pk;
  }
  __syncthreads();

  u16* DA = Dbuf0;
  u16* DB = Dbuf1;
  for (int stg = 0; stg < 6; ++stg) {
    u16* Dr = DA;
    u16* Dc = DA + 4096;
    short8 da0 = *(const short8*)&Dr[sw16(wv * 16 + fr, 0 + fq * 8, 64)];
    short8 da1 = *(const short8*)&Dr[sw16(wv * 16 + fr, 32 + fq * 8, 64)];
#pragma unroll
    for (int ct = 0; ct < 16; ++ct) {
      short8 b0 = *(const short8*)&Xb[sw16(ct * 16 + fr, 0 + fq * 8, 64)];
      short8 b1 = *(const short8*)&Xb[sw16(ct * 16 + fr, 32 + fq * 8, 64)];
      acc[ct] = MFMA16(da0, b0, acc[ct]);
      acc[ct] = MFMA16(da1, b1, acc[ct]);
    }
    f32x4 sq[4] = {};
    if (stg < 5) {
#pragma unroll
      for (int ct = 0; ct < 4; ++ct) {
        short8 sb0 = *(const short8*)&Dc[sw16(ct * 16 + fr, 0 + fq * 8, 64)];
        short8 sb1 = *(const short8*)&Dc[sw16(ct * 16 + fr, 32 + fq * 8, 64)];
        sq[ct] = MFMA16(da0, sb0, sq[ct]);
        sq[ct] = MFMA16(da1, sb1, sq[ct]);
      }
    }
    __syncthreads();
#pragma unroll
    for (int ct = 0; ct < 16; ++ct) {
      u16x4 pk;
      pk[0] = f2bf(acc[ct][0]); pk[1] = f2bf(acc[ct][1]); pk[2] = f2bf(acc[ct][2]); pk[3] = f2bf(acc[ct][3]);
      *(u16x4*)&Xb[sw16(ct * 16 + fr, wv * 16 + fq * 4, 64)] = pk;
    }
    if (stg < 5) {
#pragma unroll
      for (int ct = 0; ct < 4; ++ct) {
        u16x4 pk;
        pk[0] = f2bf(sq[ct][0]); pk[1] = f2bf(sq[ct][1]); pk[2] = f2bf(sq[ct][2]); pk[3] = f2bf(sq[ct][3]);
        *(u16x4*)&(DB + 4096)[sw16(ct * 16 + fr, wv * 16 + fq * 4, 64)] = pk;
#pragma unroll
        for (int e = 0; e < 4; ++e) DB[sw16(wv * 16 + fq * 4 + e, ct * 16 + fr, 64)] = pk[e];
      }
    }
    __syncthreads();
    u16* tmp = DA; DA = DB; DB = tmp;
  }

#pragma unroll
  for (int ct = 0; ct < 16; ++ct) {
    const int c = ct * 16 + fr;
#pragma unroll
    for (int e = 0; e < 4; ++e) {
      const int t = wv * 16 + fq * 4 + e;
      float v = acc[ct][e];
      if (ct >= 8) v = -v;
      UM_g[((size_t)pair * 64 + t) * 256 + c] = f2bf(v);
    }
  }
}

// ---------------- sequential chunk scan (minimal critical path) ----------------
// 64 blocks = (hv, dv-half cs); 8 waves. Per chunk: delta = U+(-M)@S; o1 = e^{Lt}(Q@S);
// S = e^{L63}S + Kbar^T@delta (register accumulators). Stores delta^T (pre-swizzled, into
// qkvz's dead v-columns) and o1 (e^{Lt}-scaled, swizzled rows) for the parallel k_r3.
__global__ __launch_bounds__(512)
void k_r2(u16* __restrict__ qkvz, const u16* __restrict__ UM_g,
          const float* __restrict__ cumL_g, u16* __restrict__ o1_g) {
  const int hv = blockIdx.x >> 1, cs = blockIdx.x & 1;
  const int hk = hv >> 1;
  const int tid = threadIdx.x, lane = tid & 63, w = tid >> 6;   // 8 waves
  const int fr = lane & 15, fq = lane >> 4;
  const int j = tid & 63, h = tid >> 6;                          // staging coords

  __shared__ __align__(16) u16 Ml2[2][8192];   // -M rows [t][dk] swz
  __shared__ __align__(16) u16 Ql2[2][8192];   // q rows
  __shared__ __align__(16) u16 Kt2[2][8192];   // Kbar^T [dk][t] swz
  __shared__ __align__(16) u16 Ul2[2][4096];   // U^T slice [ldv][t] swz
  __shared__ __align__(16) u16 dT[4096];       // delta^T slice [ldv][t] swz
  __shared__ __align__(16) u16 SbT[8192];      // S^T slice [ldv][dk] swz
  __shared__ __align__(16) u16 o1b[4096];      // o1 slice [t][ldv] swz
  __shared__ float Lc2[2][64];

  const int tw = w & 3;            // ph1 t-tile
  const int d0 = (w >> 2) * 2;     // ph1 dv-tile pair

  f32x4 sacc[4];
#pragma unroll
  for (int d = 0; d < 4; ++d) sacc[d] = (f32x4){0.f, 0.f, 0.f, 0.f};
  for (int i = tid; i < 8192; i += 512) SbT[i] = 0;

  u16x8 pQ0, pQ1, pK0, pK1, pM0, pM1, pU0;
  float pL, pL63;

#define PREF(nn) {                                                            \
    const int nc = ((nn) < 64) ? (nn) : 63;                                   \
    const int pr = hv * 64 + nc; const int tt0 = nc * 64;                     \
    const u16* qg = qkvz + (size_t)(tt0 + j) * NTOT + hk * DKK + h * 16;      \
    pQ0 = *(const u16x8*)qg;          pQ1 = *(const u16x8*)(qg + 8);          \
    pK0 = *(const u16x8*)(qg + 2048); pK1 = *(const u16x8*)(qg + 2056);       \
    const u16* mg = UM_g + ((size_t)pr * 64 + j) * 256;                       \
    pM0 = *(const u16x8*)(mg + 128 + h * 16);                                 \
    pM1 = *(const u16x8*)(mg + 136 + h * 16);                                 \
    pU0 = *(const u16x8*)(mg + cs * 64 + h * 8);                              \
    pL = cumL_g[(size_t)pr * 64 + j]; pL63 = cumL_g[(size_t)pr * 64 + 63]; }

#define STW(b) {                                                              \
    *(u16x8*)&Ql2[b][sw16(j, h * 16, 128)] = pQ0;                             \
    *(u16x8*)&Ql2[b][sw16(j, h * 16 + 8, 128)] = pQ1;                         \
    *(u16x8*)&Ml2[b][sw16(j, h * 16, 128)] = pM0;                             \
    *(u16x8*)&Ml2[b][sw16(j, h * 16 + 8, 128)] = pM1;                         \
    const float scK = __expf(pL63 - pL);                                      \
    _Pragma("unroll")                                                         \
    for (int e = 0; e < 8; ++e) {                                             \
      Kt2[b][sw16(h * 16 + e, j, 64)] = f2bf(scK * b2f(pK0[e]));              \
      Kt2[b][sw16(h * 16 + 8 + e, j, 64)] = f2bf(scK * b2f(pK1[e]));          \
      Ul2[b][sw16(h * 8 + e, j, 64)] = pU0[e];                                \
    }                                                                         \
    if (h == 0) Lc2[b][j] = pL; }

  PREF(0)
  STW(0)
  __syncthreads();

  for (int n = 0; n < 64; ++n) {
    const int cur = n & 1;
    const int pair = hv * 64 + n, t0 = n * 64;
    const float curL63 = pL63;
    PREF(n + 1)

    // ---- ph1: delta = U + (-M)@S ; o1 = e^{Lt}(Q@S) ----
    short8 amf[4], aqf[4];
#pragma unroll
    for (int ks = 0; ks < 4; ++ks) {
      amf[ks] = *(const short8*)&Ml2[cur][sw16(tw * 16 + fr, ks * 32 + fq * 8, 128)];
      aqf[ks] = *(const short8*)&Ql2[cur][sw16(tw * 16 + fr, ks * 32 + fq * 8, 128)];
    }
    float el[4];
#pragma unroll
    for (int e = 0; e < 4; ++e) el[e] = __expf(Lc2[cur][tw * 16 + fq * 4 + e]);
#pragma unroll
    for (int dd = 0; dd < 2; ++dd) {
      const int d = d0 + dd;
      u16x4 uv = *(const u16x4*)&Ul2[cur][sw16(d * 16 + fr, tw * 16 + fq * 4, 64)];
      f32x4 dc;
      dc[0] = b2f(uv[0]); dc[1] = b2f(uv[1]); dc[2] = b2f(uv[2]); dc[3] = b2f(uv[3]);
      f32x4 oc = {};
#pragma unroll
      for (int ks = 0; ks < 4; ++ks) {
        short8 bs = *(const short8*)&SbT[sw16(d * 16 + fr, ks * 32 + fq * 8, 128)];
        dc = MFMA16(amf[ks], bs, dc);
        oc = MFMA16(aqf[ks], bs, oc);
      }
      u16x4 pk;
      pk[0] = f2bf(dc[0]); pk[1] = f2bf(dc[1]); pk[2] = f2bf(dc[2]); pk[3] = f2bf(dc[3]);
      *(u16x4*)&dT[sw16(d * 16 + fr, tw * 16 + fq * 4, 64)] = pk;
#pragma unroll
      for (int e = 0; e < 4; ++e)
        o1b[sw16(tw * 16 + fq * 4 + e, d * 16 + fr, 64)] = f2bf(oc[e] * el[e]);
    }
    __syncthreads();

    // ---- ph2: flush delta/o1 to global; stage next; S-update ----
    {
      const int i = tid * 8;
      u16x8 vd = *(const u16x8*)&dT[i];
      const int f = cs * 4096 + i;
      *(u16x8*)(qkvz + (size_t)(t0 + (f >> 7)) * NTOT + 4096 + hv * DKK + (f & 127)) = vd;
      u16x8 vo = *(const u16x8*)&o1b[i];
      *(u16x8*)(o1_g + (size_t)pair * 8192 + (size_t)(i >> 6) * 128 + cs * 64 + (i & 63)) = vo;
    }
    STW(cur ^ 1)
    {
      const float eC = __expf(curL63);
      short8 ak0 = *(const short8*)&Kt2[cur][sw16(w * 16 + fr, fq * 8, 64)];
      short8 ak1 = *(const short8*)&Kt2[cur][sw16(w * 16 + fr, 32 + fq * 8, 64)];
#pragma unroll
      for (int d = 0; d < 4; ++d) {
        short8 bd0 = *(const short8*)&dT[sw16(d * 16 + fr, fq * 8, 64)];
        short8 bd1 = *(const short8*)&dT[sw16(d * 16 + fr, 32 + fq * 8, 64)];
        f32x4 sa = sacc[d];
#pragma unroll
        for (int e = 0; e < 4; ++e) sa[e] *= eC;
        sa = MFMA16(ak0, bd0, sa);
        sa = MFMA16(ak1, bd1, sa);
        sacc[d] = sa;
        u16x4 pk;
        pk[0] = f2bf(sa[0]); pk[1] = f2bf(sa[1]); pk[2] = f2bf(sa[2]); pk[3] = f2bf(sa[3]);
        *(u16x4*)&SbT[sw16(d * 16 + fr, w * 16 + fq * 4, 128)] = pk;
      }
    }
    __syncthreads();
  }
#undef PREF
#undef STW
}

// ---------------- parallel epilogue: o = o1 + G@delta, fused gated RMSNorm ----------------
// one block per (hv, chunk); recomputes G = tril(e^{dL} QK^T); delta^T gathered pre-swizzled
// from qkvz v-columns via global_load_lds; writes xbuf rows directly.
__global__ __launch_bounds__(512)
void k_r3(const u16* __restrict__ qkvz, const u16* __restrict__ o1_g,
          const float* __restrict__ cumL_g, const float* __restrict__ nw,
          u16* __restrict__ x) {
  const int pair = blockIdx.x, hv = pair >> 6, n = pair & 63, hk = hv >> 1, t0 = n * 64;
  const int tid = threadIdx.x, lane = tid & 63, w = tid >> 6;
  const int fr = lane & 15, fq = lane >> 4;
  const int j = tid & 63, h = tid >> 6;   // h 0..7

  __shared__ __align__(16) u16 Ql[8192];
  __shared__ __align__(16) u16 Kl[8192];
  __shared__ __align__(16) u16 Gl[4096];
  __shared__ __align__(16) u16 dTl[8192];
  __shared__ __align__(16) float of[64 * 132];
  __shared__ float Lc[64];
  __shared__ float Lw[128];

  {
    const u16* qg = qkvz + (size_t)(t0 + j) * NTOT + hk * DKK + h * 16;
    u16x8 q0 = *(const u16x8*)qg, q1 = *(const u16x8*)(qg + 8);
    u16x8 k0 = *(const u16x8*)(qg + 2048), k1 = *(const u16x8*)(qg + 2056);
    *(u16x8*)&Ql[sw16(j, h * 16, 128)] = q0;
    *(u16x8*)&Ql[sw16(j, h * 16 + 8, 128)] = q1;
    *(u16x8*)&Kl[sw16(j, h * 16, 128)] = k0;
    *(u16x8*)&Kl[sw16(j, h * 16 + 8, 128)] = k1;
  }
#pragma unroll
  for (int it = 0; it < 2; ++it) {
    const int f = ((w * 2 + it) * 64 + lane) * 8;
    gld16(qkvz + (size_t)(t0 + (f >> 7)) * NTOT + 4096 + hv * DKK + (f & 127),
          (char*)dTl + (w * 2 + it) * 1024);
  }
  if (tid < 64) Lc[tid] = cumL_g[(size_t)pair * 64 + tid];
  if (tid < 128) Lw[tid] = nw[tid];
  __syncthreads();

  // ---- G = tril(e^{Lt-Ls} * QK^T) ----
  const int tw = w & 3, sp = (w >> 2) * 2;
  {
    f32x4 kk0 = {}, kk1 = {};
#pragma unroll
    for (int ks = 0; ks < 4; ++ks) {
      short8 aq = *(const short8*)&Ql[sw16(tw * 16 + fr, ks * 32 + fq * 8, 128)];
      short8 b0 = *(const short8*)&Kl[sw16(sp * 16 + fr, ks * 32 + fq * 8, 128)];
      short8 b1 = *(const short8*)&Kl[sw16((sp + 1) * 16 + fr, ks * 32 + fq * 8, 128)];
      kk0 = MFMA16(aq, b0, kk0);
      kk1 = MFMA16(aq, b1, kk1);
    }
#pragma unroll
    for (int e = 0; e < 4; ++e) {
      const int t = tw * 16 + fq * 4 + e;
      const float Lt = Lc[t];
      const int s0 = sp * 16 + fr, s1 = s0 + 16;
      Gl[sw16(t, s0, 64)] = f2bf((s0 <= t) ? kk0[e] * __expf(Lt - Lc[s0]) : 0.f);
      Gl[sw16(t, s1, 64)] = f2bf((s1 <= t) ? kk1[e] * __expf(Lt - Lc[s1]) : 0.f);
    }
  }
  __syncthreads();

  // ---- o = G@delta ----
  {
    short8 ag0 = *(const short8*)&Gl[sw16(tw * 16 + fr, fq * 8, 64)];
    short8 ag1 = *(const short8*)&Gl[sw16(tw * 16 + fr, 32 + fq * 8, 64)];
#pragma unroll
    for (int dd = 0; dd < 4; ++dd) {
      const int d = (w >> 2) * 4 + dd;
      short8 bd0 = *(const short8*)&dTl[sw16(d * 16 + fr, fq * 8, 64)];
      short8 bd1 = *(const short8*)&dTl[sw16(d * 16 + fr, 32 + fq * 8, 64)];
      f32x4 oc = {};
      oc = MFMA16(ag0, bd0, oc);
      oc = MFMA16(ag1, bd1, oc);
#pragma unroll
      for (int e = 0; e < 4; ++e) of[(tw * 16 + fq * 4 + e) * 132 + d * 16 + fr] = oc[e];
    }
  }
  __syncthreads();

  // ---- fused gated RMSNorm: x = rmsnorm((of + o1) * silu(z)) * w ----
  {
    const int t = tid >> 3, q8 = tid & 7;
    const u16* zp = qkvz + (size_t)(t0 + t) * NTOT + 8192 + hv * DKK + q8 * 16;
    const u16* op = o1_g + (size_t)pair * 8192 + t * 128;
    float xv[16];
    float ss = 0.f;
#pragma unroll
    for (int i = 0; i < 2; ++i) {
      u16x8 zv = *(const u16x8*)(zp + i * 8);
      u16x8 ov = *(const u16x8*)(op + (((q8 * 16 + i * 8) ^ ((t & 7) << 3))));
#pragma unroll
      for (int e = 0; e < 8; ++e) {
        float z = b2f(zv[e]);
        float o = of[t * 132 + q8 * 16 + i * 8 + e] + b2f(ov[e]);
        float xx = o * (z / (1.f + __expf(-z)));
        xv[i * 8 + e] = xx;
        ss = fmaf(xx, xx, ss);
      }
    }
    ss += __shfl_xor(ss, 1);
    ss += __shfl_xor(ss, 2);
    ss += __shfl_xor(ss, 4);
    const float scl = rsqrtf(ss * (1.f / 128.f) + 1e-6f);
    u16* xo = x + (size_t)(t0 + t) * 4096 + hv * DKK + q8 * 16;
#pragma unroll
    for (int i = 0; i < 2; ++i) {
      u16x8 pk;
#pragma unroll
      for (int e = 0; e < 8; ++e) pk[e] = f2bf(xv[i * 8 + e] * scl * Lw[q8 * 16 + i * 8 + e]);
      *(u16x8*)(xo + i * 8) = pk;
    }
  }
}

extern "C" void kernel_launch(void* const* d_in, const int* in_sizes, int n_in,
                              void* d_out, int out_size, void* d_ws, size_t ws_size,
                              hipStream_t stream) {
  const float* h    = (const float*)d_in[0];
  const float* Wq   = (const float*)d_in[1];
  const float* Wk   = (const float*)d_in[2];
  const float* Wv   = (const float*)d_in[3];
  const float* Wz   = (const float*)d_in[4];
  const float* Wb   = (const float*)d_in[5];
  const float* Wa   = (const float*)d_in[6];
  const float* Alog = (const float*)d_in[7];
  const float* dtb  = (const float*)d_in[8];
  const float* nw   = (const float*)d_in[9];
  const float* Wo   = (const float*)d_in[10];
  char* ws = (char*)d_ws;
  // layout: UM 0..64M (aliased earlier by h_bf+Wt, later by xbuf) | Wto 67.1M |
  // qkvz 83.9..184.5M (delta stored into dead v-columns) | o1 184.5..216.6M | beta/g/cumL 218.1M
  u16* h_bf  = (u16*)(ws);
  u16* Wt    = (u16*)(ws + 16777216ull);
  u16* UM    = (u16*)(ws);                    // [2048][64][256] bf16 = 64MB (after GEMM)
  u16* Wto   = (u16*)(ws + 67108864ull);
  u16* qkvz  = (u16*)(ws + 83886080ull);
  u16* o1g   = (u16*)(ws + 184549376ull);     // [2048][64][128] bf16 = 32MB
  u16* xbuf  = (u16*)(ws + 16777216ull);      // aliases UM tail (dead after k_r2)
  float* beta  = (float*)(ws + 218103808ull);
  float* g     = (float*)(ws + 218103808ull + 524288ull);
  float* cumL  = (float*)(ws + 218103808ull + 1048576ull);

  k_cvt<<<8192, 256, 0, stream>>>(h, h_bf, LTOK * DHID);
  k_tr<<<dim3(64, 64), 256, 0, stream>>>(Wq, Wt, 2048, 2048);
  k_tr<<<dim3(64, 64), 256, 0, stream>>>(Wk, Wt + 2048ull * 2048, 2048, 2048);
  k_tr<<<dim3(128, 64), 256, 0, stream>>>(Wv, Wt + 4096ull * 2048, 2048, 4096);
  k_tr<<<dim3(128, 64), 256, 0, stream>>>(Wz, Wt + 8192ull * 2048, 2048, 4096);
  k_tr<<<dim3(64, 128), 256, 0, stream>>>(Wo, Wto, 4096, 2048);
  k_gemm<u16><<<dim3(96, 32), 256, 0, stream>>>(h_bf, Wt, qkvz, 4096, 12288, 2048);
  k_ba<<<1024, 256, 0, stream>>>(h, Wb, Wa, Alog, dtb, beta, g);
  k_l2n<<<32768, 256, 0, stream>>>(qkvz);
  k_r1<<<2048, 256, 0, stream>>>(qkvz, beta, g, UM, cumL);
  k_r2<<<64, 512, 0, stream>>>(qkvz, UM, cumL, o1g);
  k_r3<<<2048, 512, 0, stream>>>(qkvz, o1g, cumL, nw, xbuf);
  k_gemm<float><<<dim3(16, 32), 256, 0, stream>>>(xbuf, Wto, (float*)d_out, 4096, 2048, 4096);
}